// Round 7
// baseline (2571.070 us; speedup 1.0000x reference)
//
#include <hip/hip_runtime.h>
#include <math.h>

#define SDIM 2048
#define BATCH 1024
#define NITER 16
#define LM 64   // Lanczos steps

typedef unsigned short ushort_t;
typedef __attribute__((ext_vector_type(8))) short bf16x8;
typedef __attribute__((ext_vector_type(4))) float f32x4;

#define MFMA(a,b,c) __builtin_amdgcn_mfma_f32_16x16x32_bf16((a),(b),(c),0,0,0)

__device__ __forceinline__ float softt(float v, float th){
  return copysignf(fmaxf(fabsf(v) - th, 0.0f), v);
}

__device__ __forceinline__ float bf2f(ushort_t h){
  return __uint_as_float(((unsigned)h) << 16);
}

// RTNE float -> bf16 hi + bf16 lo split
__device__ __forceinline__ void split2(float x, ushort_t* h, ushort_t* l){
  unsigned u = __float_as_uint(x);
  unsigned hh = (u + 0x7FFFu + ((u >> 16) & 1u)) >> 16;
  float hf = __uint_as_float(hh << 16);
  float r = x - hf;                       // exact
  unsigned v = __float_as_uint(r);
  unsigned ll = (v + 0x7FFFu + ((v >> 16) & 1u)) >> 16;
  *h = (ushort_t)hh; *l = (ushort_t)ll;
}

// async 16B global -> LDS
__device__ __forceinline__ void cp16(const ushort_t* g, ushort_t* l){
  __builtin_amdgcn_global_load_lds(
      (const __attribute__((address_space(1))) unsigned int*)g,
      (__attribute__((address_space(3))) unsigned int*)l, 16, 0, 0);
}

// ---------------- MFMA GEMM core (r3 4-wave + ping-pong dbuf) ----------------
// C[m][n] = sum_k A[m][k]*B[n][k], A,B row-major bf16 hi/lo split.
// 64x64 tile, BK=64, 256 threads = 4 waves of 32x32 output each.
// Ping-pong: stage tile kt+1 (async cp16, no wait), compute tile kt, ONE
// barrier per kt -- the vmcnt(0) drain before s_barrier lands after the full
// compute phase, so staging latency is hidden. 64KB LDS -> 2 blocks/CU.
// LDS layout (proven 0 bank conflicts): chunk (row r, kchunk kp) at
// ushort offset r*64 + (kp^(r&7))*8; staging chunk tid(+256) lane-linear.
__device__ __forceinline__ void gemm_core(const ushort_t* __restrict__ Ah, const ushort_t* __restrict__ Al,
                                          const ushort_t* __restrict__ Bh, const ushort_t* __restrict__ Bl,
                                          int m0, int n0, int K, f32x4 acc[2][2])
{
  __shared__ ushort_t lAh[2][64*64], lAl[2][64*64], lBh[2][64*64], lBl[2][64*64];
  const int tid = threadIdx.x;
  const int rr = tid >> 3;
  const int kp = (tid & 7) ^ (rr & 7);
  const size_t strA = (size_t)32 * K;
  const ushort_t* gAh = Ah + (size_t)(m0 + rr) * K + kp * 8;
  const ushort_t* gAl = Al + (size_t)(m0 + rr) * K + kp * 8;
  const ushort_t* gBh = Bh + (size_t)(n0 + rr) * K + kp * 8;
  const ushort_t* gBl = Bl + (size_t)(n0 + rr) * K + kp * 8;
  const int d0 = tid * 8, d1 = (tid + 256) * 8;

  const int lane = tid & 63, wv = tid >> 6;
  const int wm = (wv >> 1) * 32, wn = (wv & 1) * 32;
  const int mm = lane & 15, quad = lane >> 4;
  const int ra0 = wm + mm, ra1 = wm + 16 + mm;
  const int rb0 = wn + mm, rb1 = wn + 16 + mm;

  const int nk = K / 64;
  // prologue: stage tile 0
  cp16(gAh, &lAh[0][d0]); cp16(gAh + strA, &lAh[0][d1]);
  cp16(gAl, &lAl[0][d0]); cp16(gAl + strA, &lAl[0][d1]);
  cp16(gBh, &lBh[0][d0]); cp16(gBh + strA, &lBh[0][d1]);
  cp16(gBl, &lBl[0][d0]); cp16(gBl + strA, &lBl[0][d1]);
  gAh += 64; gAl += 64; gBh += 64; gBl += 64;
  __syncthreads();

  for (int kt = 0; kt < nk; kt++){
    const int cur = kt & 1, nxt = 1 - cur;
    if (kt + 1 < nk){
      cp16(gAh, &lAh[nxt][d0]); cp16(gAh + strA, &lAh[nxt][d1]);
      cp16(gAl, &lAl[nxt][d0]); cp16(gAl + strA, &lAl[nxt][d1]);
      cp16(gBh, &lBh[nxt][d0]); cp16(gBh + strA, &lBh[nxt][d1]);
      cp16(gBl, &lBl[nxt][d0]); cp16(gBl + strA, &lBl[nxt][d1]);
      gAh += 64; gAl += 64; gBh += 64; gBl += 64;
    }
    #pragma unroll
    for (int u = 0; u < 2; u++){
      const int oa0 = ra0*64 + (((u*4 + quad) ^ (ra0 & 7)) << 3);
      const int oa1 = ra1*64 + (((u*4 + quad) ^ (ra1 & 7)) << 3);
      const int ob0 = rb0*64 + (((u*4 + quad) ^ (rb0 & 7)) << 3);
      const int ob1 = rb1*64 + (((u*4 + quad) ^ (rb1 & 7)) << 3);
      bf16x8 ah0 = *(const bf16x8*)&lAh[cur][oa0];
      bf16x8 ah1 = *(const bf16x8*)&lAh[cur][oa1];
      bf16x8 al0 = *(const bf16x8*)&lAl[cur][oa0];
      bf16x8 al1 = *(const bf16x8*)&lAl[cur][oa1];
      bf16x8 bh0 = *(const bf16x8*)&lBh[cur][ob0];
      bf16x8 bh1 = *(const bf16x8*)&lBh[cur][ob1];
      bf16x8 bl0 = *(const bf16x8*)&lBl[cur][ob0];
      bf16x8 bl1 = *(const bf16x8*)&lBl[cur][ob1];
      acc[0][0] = MFMA(ah0, bh0, acc[0][0]);
      acc[0][0] = MFMA(ah0, bl0, acc[0][0]);
      acc[0][0] = MFMA(al0, bh0, acc[0][0]);
      acc[0][1] = MFMA(ah0, bh1, acc[0][1]);
      acc[0][1] = MFMA(ah0, bl1, acc[0][1]);
      acc[0][1] = MFMA(al0, bh1, acc[0][1]);
      acc[1][0] = MFMA(ah1, bh0, acc[1][0]);
      acc[1][0] = MFMA(ah1, bl0, acc[1][0]);
      acc[1][0] = MFMA(al1, bh0, acc[1][0]);
      acc[1][1] = MFMA(ah1, bh1, acc[1][1]);
      acc[1][1] = MFMA(ah1, bl1, acc[1][1]);
      acc[1][1] = MFMA(al1, bh1, acc[1][1]);
    }
    __syncthreads();   // drains in-flight staging (overlapped by compute above)
  }
}

// ---------------- W split / transpose-split ----------------
__global__ __launch_bounds__(256) void k_split(const float* __restrict__ W,
                                               ushort_t* __restrict__ Wah, ushort_t* __restrict__ Wal,
                                               ushort_t* __restrict__ Wbh, ushort_t* __restrict__ Wbl){
  __shared__ float t[32][33];
  const int i0 = blockIdx.y * 32, j0 = blockIdx.x * 32;
  const int r = threadIdx.x >> 3, c = (threadIdx.x & 7) * 4;
  const float4 v = *(const float4*)&W[(size_t)(i0 + r) * SDIM + j0 + c];
  float vv[4] = {v.x, v.y, v.z, v.w};
  ushort_t h[4], l[4];
  #pragma unroll
  for (int q = 0; q < 4; q++){ split2(vv[q], &h[q], &l[q]); t[r][c+q] = vv[q]; }
  *(ushort4*)&Wah[(size_t)(i0 + r) * SDIM + j0 + c] = make_ushort4(h[0],h[1],h[2],h[3]);
  *(ushort4*)&Wal[(size_t)(i0 + r) * SDIM + j0 + c] = make_ushort4(l[0],l[1],l[2],l[3]);
  __syncthreads();
  #pragma unroll
  for (int q = 0; q < 4; q++) split2(t[c+q][r], &h[q], &l[q]);
  *(ushort4*)&Wbh[(size_t)(j0 + r) * SDIM + i0 + c] = make_ushort4(h[0],h[1],h[2],h[3]);
  *(ushort4*)&Wbl[(size_t)(j0 + r) * SDIM + i0 + c] = make_ushort4(l[0],l[1],l[2],l[3]);
}

// M = W * W^T (same nonzero spectrum as W^T W)
__global__ __launch_bounds__(256) void k_gemmM(const ushort_t* __restrict__ Wah, const ushort_t* __restrict__ Wal,
                                               float* __restrict__ Mmat){
  f32x4 acc[2][2] = {};
  const int m0 = blockIdx.y * 64, n0 = blockIdx.x * 64;
  gemm_core(Wah, Wal, Wah, Wal, m0, n0, SDIM, acc);
  const int tid = threadIdx.x, lane = tid & 63, wv = tid >> 6;
  const int wm = (wv >> 1) * 32, wn = (wv & 1) * 32;
  const int mm = lane & 15, quad = lane >> 4;
  #pragma unroll
  for (int tm = 0; tm < 2; tm++)
    #pragma unroll
    for (int tn = 0; tn < 2; tn++)
      #pragma unroll
      for (int i = 0; i < 4; i++){
        int row = m0 + wm + tm*16 + quad*4 + i;
        int col = n0 + wn + tn*16 + mm;
        Mmat[(size_t)row * SDIM + col] = acc[tm][tn][i];
      }
}

// ---------------- Lanczos on M: one kernel per step ----------------
__global__ __launch_bounds__(256) void k_init(float* __restrict__ vRing,
                                              double* __restrict__ dotWV, double* __restrict__ dotWW,
                                              float* __restrict__ betaSq){
  __shared__ float red[256];
  int t = threadIdx.x;
  float vals[8];
  float s = 0.f;
  #pragma unroll
  for (int p = 0; p < 8; p++){
    int j = p*256 + t;
    unsigned h = (unsigned)j * 2654435761u;
    h ^= h >> 16; h *= 2246822519u; h ^= h >> 13;
    float r = (float)(h & 0xFFFFFFu) / 16777216.0f - 0.5f;
    vals[p] = r; s += r*r;
  }
  red[t] = s; __syncthreads();
  for (int o = 128; o > 0; o >>= 1){ if (t < o) red[t] += red[t+o]; __syncthreads(); }
  float inv = rsqrtf(red[0]);
  #pragma unroll
  for (int p = 0; p < 8; p++){
    int j = p*256 + t;
    vRing[SDIM + j] = vals[p]*inv;   // slot 1 = v_1
    vRing[j] = 0.f;                  // slot 0
    vRing[2*SDIM + j] = 0.f;         // slot 2
  }
  if (t < LM+2){ dotWV[t] = 0.0; dotWW[t] = 0.0; betaSq[t] = 0.f; }
}

// step s: reconstruct v_s from w_{s-1} (redundant per block), then 4 rows of M v_s.
// beta^2_{s-1} = ||w||^2 - alpha^2 - beta^2_{s-2}  (fp64 scalar chain)
__global__ __launch_bounds__(256) void k_lstep(const float* __restrict__ M,
    const float* __restrict__ wOld, float* __restrict__ wNew,
    float* __restrict__ vRing, double* __restrict__ dotWV, double* __restrict__ dotWW,
    float* __restrict__ betaSq, int s){
  __shared__ float vs[SDIM];
  __shared__ double pAl[4], pWw[4];
  const int tid = threadIdx.x, bid = blockIdx.x;
  if (s == 1){
    const float* v1 = vRing + SDIM;
    for (int j = tid; j < SDIM; j += 256) vs[j] = v1[j];
  } else {
    const double a  = dotWV[s-1];
    const double ww = dotWW[s-1];
    const float bpSq = betaSq[s-2];
    float bsq = (float)(ww - a*a - (double)bpSq);
    bsq = fmaxf(bsq, 1e-20f);
    const float beta = sqrtf(bsq), invb = 1.0f/beta;
    const float alpha = (float)a, bprev = sqrtf(bpSq);
    const float* vm1 = vRing + ((s-1)%3)*SDIM;
    const float* vm2 = vRing + ((s-2)%3)*SDIM;
    float* vdst = vRing + (s%3)*SDIM;
    for (int j = tid; j < SDIM; j += 256){
      float val = (wOld[j] - alpha*vm1[j] - bprev*vm2[j]) * invb;
      vs[j] = val;
      if (bid == 0) vdst[j] = val;
    }
    if (bid == 0 && tid == 0) betaSq[s-1] = bsq;
  }
  __syncthreads();
  const int wv = tid >> 6, lane = tid & 63;
  const int row = bid*4 + wv;
  const float4* Mr = (const float4*)(M + (size_t)row * SDIM);
  const float4* v4 = (const float4*)vs;
  float acc = 0.f;
  #pragma unroll
  for (int p = 0; p < 8; p++){
    int j4 = p*64 + lane;
    float4 m = Mr[j4], v = v4[j4];
    acc += m.x*v.x + m.y*v.y + m.z*v.z + m.w*v.w;
  }
  #pragma unroll
  for (int o = 32; o > 0; o >>= 1) acc += __shfl_down(acc, o);
  if (lane == 0){
    wNew[row] = acc;
    pAl[wv] = (double)acc * (double)vs[row];
    pWw[wv] = (double)acc * (double)acc;
  }
  __syncthreads();
  if (tid == 0){
    atomicAdd(&dotWV[s], pAl[0]+pAl[1]+pAl[2]+pAl[3]);
    atomicAdd(&dotWW[s], pWw[0]+pWw[1]+pWw[2]+pWw[3]);
  }
}

// lambda_max of tridiagonal via lane-parallel Sturm bisection (fp64)
__global__ void k_sturm(const double* __restrict__ dotWV, const float* __restrict__ betaSq,
                        const float* __restrict__ alphaIn, float* __restrict__ Lbuf){
  __shared__ double sa[LM+1], sb[LM+1];
  int lane = threadIdx.x;
  for (int i = lane; i <= LM; i += 64){
    if (i >= 1){
      sa[i] = dotWV[i];
      sb[i] = (i < LM) ? sqrt((double)betaSq[i]) : 0.0;
    }
  }
  __syncthreads();
  double phi = -1e300, plo = 1e300;
  for (int i = 1 + lane; i <= LM; i += 64){
    double r = (i > 1 ? sb[i-1] : 0.0) + (i < LM ? sb[i] : 0.0);
    phi = fmax(phi, sa[i] + r);
    plo = fmin(plo, sa[i] - r);
  }
  for (int o = 32; o > 0; o >>= 1){
    phi = fmax(phi, __shfl_down(phi, o));
    plo = fmin(plo, __shfl_down(plo, o));
  }
  double hi = __shfl(phi, 0), lo = __shfl(plo, 0);
  for (int round = 0; round < 6; round++){
    double x = lo + (hi - lo) * (double)(lane + 1) / 65.0;
    int cnt = 0;
    double dd = sa[1] - x;
    if (dd < 0) cnt++;
    for (int i = 2; i <= LM; i++){
      double off = sb[i-1];
      if (fabs(dd) < 1e-300) dd = -1e-300;
      dd = sa[i] - x - off*off/dd;
      if (dd < 0) cnt++;
    }
    unsigned long long bal = __ballot(cnt == LM);
    int p = (bal == 0ull) ? 64 : (__ffsll((unsigned long long)bal) - 1);
    double newhi = (p <= 63) ? lo + (hi - lo) * (double)(p + 1) / 65.0 : hi;
    double newlo = (p >= 1)  ? lo + (hi - lo) * (double)p / 65.0       : lo;
    hi = newhi; lo = newlo;
  }
  if (lane == 0){
    double L = 0.5*(lo + hi);
    Lbuf[0] = (float)(1.0 / L);
    Lbuf[1] = (float)(0.5 * (double)alphaIn[0] / L);
  }
}

// ---------------- FISTA ----------------

// iteration 0 elementwise (y0=0): sres = src*Y, delta-half update
__global__ __launch_bounds__(256) void k_A0(const float* __restrict__ Y, const float* __restrict__ src,
                                            float* __restrict__ yd, ushort_t* __restrict__ sresh,
                                            ushort_t* __restrict__ sresl, float* __restrict__ out,
                                            const float* __restrict__ Lbuf){
  int idx = blockIdx.x*256 + threadIdx.x;
  float invL = Lbuf[0], th = Lbuf[1];
  float y = Y[idx], s = src[idx];
  split2(s*y, &sresh[idx], &sresl[idx]);
  float xn = softt(y*invL, th);
  int b = idx >> 11, i = idx & 2047;
  out[(size_t)b*4096 + 2048 + i] = xn;
  yd[idx] = xn;   // c0 = 0 -> y1 = x1
}

// GEMM1: acc[b][i] = sum_k ym[b][k]*W[i][k]; fused res/sres/delta update
__global__ __launch_bounds__(256) void k_gemmA(
    const ushort_t* __restrict__ Wah, const ushort_t* __restrict__ Wal,
    const ushort_t* __restrict__ ymh, const ushort_t* __restrict__ yml,
    const float* __restrict__ Y, const float* __restrict__ src,
    float* __restrict__ yd, float* __restrict__ out,
    ushort_t* __restrict__ sresh, ushort_t* __restrict__ sresl,
    const float* __restrict__ Lbuf, float ck)
{
  f32x4 acc[2][2] = {};
  const int m0 = blockIdx.y * 64, n0 = blockIdx.x * 64;
  gemm_core(ymh, yml, Wah, Wal, m0, n0, SDIM, acc);
  const float invL = Lbuf[0], th = Lbuf[1];
  const int tid = threadIdx.x, lane = tid & 63, wv = tid >> 6;
  const int wm = (wv >> 1) * 32, wn = (wv & 1) * 32;
  const int mm = lane & 15, quad = lane >> 4;
  #pragma unroll
  for (int tm = 0; tm < 2; tm++)
    #pragma unroll
    for (int tn = 0; tn < 2; tn++)
      #pragma unroll
      for (int i = 0; i < 4; i++){
        int brow = m0 + wm + tm*16 + quad*4 + i;
        int col  = n0 + wn + tn*16 + mm;
        int g = brow*SDIM + col;
        float a = acc[tm][tn][i];
        float s = src[g], ydv = yd[g];
        float res = Y[g] - s*a - ydv;
        split2(s*res, &sresh[g], &sresl[g]);
        float xn = softt(ydv + res*invL, th);
        int go = brow*4096 + 2048 + col;
        float xo = out[go];
        out[go] = xn;
        yd[g] = xn + ck*(xn - xo);
      }
}

// GEMM2: acc[b][j] = sum_i sres[b][i]*W[i][j]; fused theta update
template<bool FIRST>
__global__ __launch_bounds__(256) void k_gemmB(
    const ushort_t* __restrict__ Wbh, const ushort_t* __restrict__ Wbl,
    const ushort_t* __restrict__ sresh, const ushort_t* __restrict__ sresl,
    ushort_t* __restrict__ ymh, ushort_t* __restrict__ yml,
    float* __restrict__ out, const float* __restrict__ Lbuf, float ck)
{
  f32x4 acc[2][2] = {};
  const int m0 = blockIdx.y * 64, n0 = blockIdx.x * 64;
  gemm_core(sresh, sresl, Wbh, Wbl, m0, n0, SDIM, acc);
  const float invL = Lbuf[0], th = Lbuf[1];
  const int tid = threadIdx.x, lane = tid & 63, wv = tid >> 6;
  const int wm = (wv >> 1) * 32, wn = (wv & 1) * 32;
  const int mm = lane & 15, quad = lane >> 4;
  #pragma unroll
  for (int tm = 0; tm < 2; tm++)
    #pragma unroll
    for (int tn = 0; tn < 2; tn++)
      #pragma unroll
      for (int i = 0; i < 4; i++){
        int brow = m0 + wm + tm*16 + quad*4 + i;
        int col  = n0 + wn + tn*16 + mm;
        int g = brow*SDIM + col;
        float a = acc[tm][tn][i];
        float ymv = FIRST ? 0.f : (bf2f(ymh[g]) + bf2f(yml[g]));
        float xn = softt(ymv + a*invL, th);
        int go = brow*4096 + col;
        float xo = FIRST ? 0.f : out[go];
        out[go] = xn;
        split2(xn + ck*(xn - xo), &ymh[g], &yml[g]);
      }
}

// ---------------- host ----------------

extern "C" void kernel_launch(void* const* d_in, const int* in_sizes, int n_in,
                              void* d_out, int out_size, void* d_ws, size_t ws_size,
                              hipStream_t stream) {
  const float* src   = (const float*)d_in[0];
  const float* Y     = (const float*)d_in[1];
  const float* W     = (const float*)d_in[2];
  const float* alpha = (const float*)d_in[3];
  float* out = (float*)d_out;
  float* ws  = (float*)d_ws;

  const size_t M1 = 1024*1024;
  float* Mmat = ws;                      // 4M floats (16MB)
  float* yd   = ws + 4*M1;               // 2M floats
  float* lanc = ws + 6*M1;
  float* w0      = lanc;                 // 2048
  float* w1      = lanc + SDIM;          // 2048
  float* vRing   = lanc + 2*SDIM;        // 3*2048
  double* dotWV  = (double*)(lanc + 5*SDIM);        // 128 doubles
  double* dotWW  = dotWV + 128;                     // 128 doubles
  float* betaSq  = lanc + 5*SDIM + 512;             // 128 floats
  float* Lbuf    = betaSq + 128;                    // 2
  ushort_t* u16 = (ushort_t*)(ws + 7*M1);
  ushort_t* Wah = u16;                   // 4M u16 each
  ushort_t* Wal = u16 + 4*M1;
  ushort_t* Wbh = u16 + 8*M1;
  ushort_t* Wbl = u16 + 12*M1;
  ushort_t* ymh = u16 + 16*M1;           // 2M u16 each
  ushort_t* yml = u16 + 18*M1;
  ushort_t* sresh = u16 + 20*M1;
  ushort_t* sresl = u16 + 22*M1;

  // ---- split W (and W^T) into bf16 hi/lo ----
  k_split<<<dim3(64,64), 256, 0, stream>>>(W, Wah, Wal, Wbh, Wbl);
  // ---- M = W W^T for Lanczos ----
  k_gemmM<<<dim3(32,32), 256, 0, stream>>>(Wah, Wal, Mmat);

  // ---- Lanczos for L = lambda_max: one kernel per step ----
  float* wb[2] = { w0, w1 };
  k_init<<<1, 256, 0, stream>>>(vRing, dotWV, dotWW, betaSq);
  for (int s = 1; s <= LM; s++){
    k_lstep<<<512, 256, 0, stream>>>(Mmat, wb[(s+1)&1], wb[s&1], vRing, dotWV, dotWW, betaSq, s);
  }
  k_sturm<<<1, 64, 0, stream>>>(dotWV, betaSq, alpha, Lbuf);

  // ---- momentum coefficients (data independent) ----
  double t = 1.0;
  float ckv[NITER];
  for (int k = 0; k < NITER; k++){
    double tn = 0.5*(1.0 + sqrt(1.0 + 4.0*t*t));
    ckv[k] = (float)((t - 1.0)/tn);
    t = tn;
  }

  // ---- FISTA ----
  k_A0<<<(BATCH*SDIM)/256, 256, 0, stream>>>(Y, src, yd, sresh, sresl, out, Lbuf);
  k_gemmB<true><<<dim3(32,16), 256, 0, stream>>>(Wbh, Wbl, sresh, sresl, ymh, yml, out, Lbuf, ckv[0]);
  for (int k = 1; k < NITER; k++){
    k_gemmA<<<dim3(32,16), 256, 0, stream>>>(Wah, Wal, ymh, yml, Y, src, yd, out, sresh, sresl, Lbuf, ckv[k]);
    k_gemmB<false><<<dim3(32,16), 256, 0, stream>>>(Wbh, Wbl, sresh, sresl, ymh, yml, out, Lbuf, ckv[k]);
  }
  (void)in_sizes; (void)n_in; (void)out_size; (void)ws_size;
}

// Round 8
// 1907.224 us; speedup vs baseline: 1.3481x; 1.3481x over previous
//
#include <hip/hip_runtime.h>
#include <math.h>

#define SDIM 2048
#define BATCH 1024
#define NITER 16
#define LM 48   // Lanczos steps

typedef unsigned short ushort_t;
typedef __attribute__((ext_vector_type(8))) short bf16x8;
typedef __attribute__((ext_vector_type(4))) float f32x4;

#define MFMA(a,b,c) __builtin_amdgcn_mfma_f32_16x16x32_bf16((a),(b),(c),0,0,0)

__device__ __forceinline__ float softt(float v, float th){
  return copysignf(fmaxf(fabsf(v) - th, 0.0f), v);
}

__device__ __forceinline__ float bf2f(ushort_t h){
  return __uint_as_float(((unsigned)h) << 16);
}

// RTNE float -> bf16 hi + bf16 lo split
__device__ __forceinline__ void split2(float x, ushort_t* h, ushort_t* l){
  unsigned u = __float_as_uint(x);
  unsigned hh = (u + 0x7FFFu + ((u >> 16) & 1u)) >> 16;
  float hf = __uint_as_float(hh << 16);
  float r = x - hf;                       // exact
  unsigned v = __float_as_uint(r);
  unsigned ll = (v + 0x7FFFu + ((v >> 16) & 1u)) >> 16;
  *h = (ushort_t)hh; *l = (ushort_t)ll;
}

// async 16B global -> LDS
__device__ __forceinline__ void cp16(const ushort_t* g, ushort_t* l){
  __builtin_amdgcn_global_load_lds(
      (const __attribute__((address_space(1))) unsigned int*)g,
      (__attribute__((address_space(3))) unsigned int*)l, 16, 0, 0);
}

// ---------------- MFMA GEMM core (r3 proven: 64x64, BK=64, 4 waves, single buffer) ----------------
// C[m][n] = sum_k A[m][k]*B[n][k], A,B row-major bf16 hi/lo split.
// LDS: chunk (row r, kchunk kp of 8) at ushort offset r*64 + (kp^(r&7))*8 —
// lane-linear for cp16, measured 0 bank conflicts. 32KB LDS -> 2 blocks/CU.
// NOTE: dbuf/ping-pong variants measured SLOWER (r4: conflicts; r7: compiler
// serializes DMA vs ds_read). Keep the 2-barrier shape.
__device__ __forceinline__ void gemm_core(const ushort_t* __restrict__ Ah, const ushort_t* __restrict__ Al,
                                          const ushort_t* __restrict__ Bh, const ushort_t* __restrict__ Bl,
                                          int m0, int n0, int K, f32x4 acc[2][2])
{
  __shared__ ushort_t lAh[64*64], lAl[64*64], lBh[64*64], lBl[64*64];
  const int tid = threadIdx.x;
  const int rr = tid >> 3;
  const int kp = (tid & 7) ^ (rr & 7);
  const size_t strA = (size_t)32 * K;
  const ushort_t* gAh = Ah + (size_t)(m0 + rr) * K + kp * 8;
  const ushort_t* gAl = Al + (size_t)(m0 + rr) * K + kp * 8;
  const ushort_t* gBh = Bh + (size_t)(n0 + rr) * K + kp * 8;
  const ushort_t* gBl = Bl + (size_t)(n0 + rr) * K + kp * 8;
  ushort_t* dA0 = &lAh[tid * 8];      ushort_t* dA1 = &lAh[(tid + 256) * 8];
  ushort_t* dAl0 = &lAl[tid * 8];     ushort_t* dAl1 = &lAl[(tid + 256) * 8];
  ushort_t* dB0 = &lBh[tid * 8];      ushort_t* dB1 = &lBh[(tid + 256) * 8];
  ushort_t* dBl0 = &lBl[tid * 8];     ushort_t* dBl1 = &lBl[(tid + 256) * 8];

  const int lane = tid & 63, wv = tid >> 6;
  const int wm = (wv >> 1) * 32, wn = (wv & 1) * 32;
  const int mm = lane & 15, quad = lane >> 4;
  const int ra0 = wm + mm, ra1 = wm + 16 + mm;
  const int rb0 = wn + mm, rb1 = wn + 16 + mm;

  const int nk = K / 64;
  for (int kt = 0; kt < nk; kt++){
    cp16(gAh, dA0); cp16(gAh + strA, dA1);
    cp16(gAl, dAl0); cp16(gAl + strA, dAl1);
    cp16(gBh, dB0); cp16(gBh + strA, dB1);
    cp16(gBl, dBl0); cp16(gBl + strA, dBl1);
    gAh += 64; gAl += 64; gBh += 64; gBl += 64;
    __syncthreads();   // drains vmcnt -> staged tile visible
    #pragma unroll
    for (int u = 0; u < 2; u++){
      const int oa0 = ra0*64 + (((u*4 + quad) ^ (ra0 & 7)) << 3);
      const int oa1 = ra1*64 + (((u*4 + quad) ^ (ra1 & 7)) << 3);
      const int ob0 = rb0*64 + (((u*4 + quad) ^ (rb0 & 7)) << 3);
      const int ob1 = rb1*64 + (((u*4 + quad) ^ (rb1 & 7)) << 3);
      bf16x8 ah0 = *(const bf16x8*)&lAh[oa0];
      bf16x8 ah1 = *(const bf16x8*)&lAh[oa1];
      bf16x8 al0 = *(const bf16x8*)&lAl[oa0];
      bf16x8 al1 = *(const bf16x8*)&lAl[oa1];
      bf16x8 bh0 = *(const bf16x8*)&lBh[ob0];
      bf16x8 bh1 = *(const bf16x8*)&lBh[ob1];
      bf16x8 bl0 = *(const bf16x8*)&lBl[ob0];
      bf16x8 bl1 = *(const bf16x8*)&lBl[ob1];
      acc[0][0] = MFMA(ah0, bh0, acc[0][0]);
      acc[0][0] = MFMA(ah0, bl0, acc[0][0]);
      acc[0][0] = MFMA(al0, bh0, acc[0][0]);
      acc[0][1] = MFMA(ah0, bh1, acc[0][1]);
      acc[0][1] = MFMA(ah0, bl1, acc[0][1]);
      acc[0][1] = MFMA(al0, bh1, acc[0][1]);
      acc[1][0] = MFMA(ah1, bh0, acc[1][0]);
      acc[1][0] = MFMA(ah1, bl0, acc[1][0]);
      acc[1][0] = MFMA(al1, bh0, acc[1][0]);
      acc[1][1] = MFMA(ah1, bh1, acc[1][1]);
      acc[1][1] = MFMA(ah1, bl1, acc[1][1]);
      acc[1][1] = MFMA(al1, bh1, acc[1][1]);
    }
    __syncthreads();   // protect LDS before next stage
  }
}

// ---------------- W split / transpose-split ----------------
__global__ __launch_bounds__(256) void k_split(const float* __restrict__ W,
                                               ushort_t* __restrict__ Wah, ushort_t* __restrict__ Wal,
                                               ushort_t* __restrict__ Wbh, ushort_t* __restrict__ Wbl){
  __shared__ float t[32][33];
  const int i0 = blockIdx.y * 32, j0 = blockIdx.x * 32;
  const int r = threadIdx.x >> 3, c = (threadIdx.x & 7) * 4;
  const float4 v = *(const float4*)&W[(size_t)(i0 + r) * SDIM + j0 + c];
  float vv[4] = {v.x, v.y, v.z, v.w};
  ushort_t h[4], l[4];
  #pragma unroll
  for (int q = 0; q < 4; q++){ split2(vv[q], &h[q], &l[q]); t[r][c+q] = vv[q]; }
  *(ushort4*)&Wah[(size_t)(i0 + r) * SDIM + j0 + c] = make_ushort4(h[0],h[1],h[2],h[3]);
  *(ushort4*)&Wal[(size_t)(i0 + r) * SDIM + j0 + c] = make_ushort4(l[0],l[1],l[2],l[3]);
  __syncthreads();
  #pragma unroll
  for (int q = 0; q < 4; q++) split2(t[c+q][r], &h[q], &l[q]);
  *(ushort4*)&Wbh[(size_t)(j0 + r) * SDIM + i0 + c] = make_ushort4(h[0],h[1],h[2],h[3]);
  *(ushort4*)&Wbl[(size_t)(j0 + r) * SDIM + i0 + c] = make_ushort4(l[0],l[1],l[2],l[3]);
}

// M = W * W^T (same nonzero spectrum as W^T W). XCD-swizzled grid (1024 blocks):
// xcd = b&7 owns n-tiles xcd*4..+4 (2MB of W h+l -> L2-resident), streams m.
__global__ __launch_bounds__(256) void k_gemmM(const ushort_t* __restrict__ Wah, const ushort_t* __restrict__ Wal,
                                               float* __restrict__ Mmat){
  const int b = blockIdx.x + (blockIdx.y << 5);
  const int xcd = b & 7, slot = b >> 3;          // slot in [0,128)
  const int n0 = (((xcd << 2) + (slot >> 5)) << 6);
  const int m0 = ((slot & 31) << 6);
  f32x4 acc[2][2] = {};
  gemm_core(Wah, Wal, Wah, Wal, m0, n0, SDIM, acc);
  const int tid = threadIdx.x, lane = tid & 63, wv = tid >> 6;
  const int wm = (wv >> 1) * 32, wn = (wv & 1) * 32;
  const int mm = lane & 15, quad = lane >> 4;
  #pragma unroll
  for (int tm = 0; tm < 2; tm++)
    #pragma unroll
    for (int tn = 0; tn < 2; tn++)
      #pragma unroll
      for (int i = 0; i < 4; i++){
        int row = m0 + wm + tm*16 + quad*4 + i;
        int col = n0 + wn + tn*16 + mm;
        Mmat[(size_t)row * SDIM + col] = acc[tm][tn][i];
      }
}

// ---------------- Lanczos on M: one kernel per step ----------------
__global__ __launch_bounds__(256) void k_init(float* __restrict__ vRing,
                                              double* __restrict__ dotWV, double* __restrict__ dotWW,
                                              float* __restrict__ betaSq){
  __shared__ float red[256];
  int t = threadIdx.x;
  float vals[8];
  float s = 0.f;
  #pragma unroll
  for (int p = 0; p < 8; p++){
    int j = p*256 + t;
    unsigned h = (unsigned)j * 2654435761u;
    h ^= h >> 16; h *= 2246822519u; h ^= h >> 13;
    float r = (float)(h & 0xFFFFFFu) / 16777216.0f - 0.5f;
    vals[p] = r; s += r*r;
  }
  red[t] = s; __syncthreads();
  for (int o = 128; o > 0; o >>= 1){ if (t < o) red[t] += red[t+o]; __syncthreads(); }
  float inv = rsqrtf(red[0]);
  #pragma unroll
  for (int p = 0; p < 8; p++){
    int j = p*256 + t;
    vRing[SDIM + j] = vals[p]*inv;   // slot 1 = v_1
    vRing[j] = 0.f;                  // slot 0
    vRing[2*SDIM + j] = 0.f;         // slot 2
  }
  if (t < LM+2){ dotWV[t] = 0.0; dotWW[t] = 0.0; betaSq[t] = 0.f; }
}

// step s: reconstruct v_s from w_{s-1} (redundant per block), then 4 rows of M v_s.
// beta^2_{s-1} = ||w||^2 - alpha^2 - beta^2_{s-2}  (fp64 scalar chain)
__global__ __launch_bounds__(256) void k_lstep(const float* __restrict__ M,
    const float* __restrict__ wOld, float* __restrict__ wNew,
    float* __restrict__ vRing, double* __restrict__ dotWV, double* __restrict__ dotWW,
    float* __restrict__ betaSq, int s){
  __shared__ float vs[SDIM];
  __shared__ double pAl[4], pWw[4];
  const int tid = threadIdx.x, bid = blockIdx.x;
  if (s == 1){
    const float* v1 = vRing + SDIM;
    for (int j = tid; j < SDIM; j += 256) vs[j] = v1[j];
  } else {
    const double a  = dotWV[s-1];
    const double ww = dotWW[s-1];
    const float bpSq = betaSq[s-2];
    float bsq = (float)(ww - a*a - (double)bpSq);
    bsq = fmaxf(bsq, 1e-20f);
    const float beta = sqrtf(bsq), invb = 1.0f/beta;
    const float alpha = (float)a, bprev = sqrtf(bpSq);
    const float* vm1 = vRing + ((s-1)%3)*SDIM;
    const float* vm2 = vRing + ((s-2)%3)*SDIM;
    float* vdst = vRing + (s%3)*SDIM;
    for (int j = tid; j < SDIM; j += 256){
      float val = (wOld[j] - alpha*vm1[j] - bprev*vm2[j]) * invb;
      vs[j] = val;
      if (bid == 0) vdst[j] = val;
    }
    if (bid == 0 && tid == 0) betaSq[s-1] = bsq;
  }
  __syncthreads();
  const int wv = tid >> 6, lane = tid & 63;
  const int row = bid*4 + wv;
  const float4* Mr = (const float4*)(M + (size_t)row * SDIM);
  const float4* v4 = (const float4*)vs;
  float acc = 0.f;
  #pragma unroll
  for (int p = 0; p < 8; p++){
    int j4 = p*64 + lane;
    float4 m = Mr[j4], v = v4[j4];
    acc += m.x*v.x + m.y*v.y + m.z*v.z + m.w*v.w;
  }
  #pragma unroll
  for (int o = 32; o > 0; o >>= 1) acc += __shfl_down(acc, o);
  if (lane == 0){
    wNew[row] = acc;
    pAl[wv] = (double)acc * (double)vs[row];
    pWw[wv] = (double)acc * (double)acc;
  }
  __syncthreads();
  if (tid == 0){
    atomicAdd(&dotWV[s], pAl[0]+pAl[1]+pAl[2]+pAl[3]);
    atomicAdd(&dotWW[s], pWw[0]+pWw[1]+pWw[2]+pWw[3]);
  }
}

// lambda_max of tridiagonal via lane-parallel Sturm bisection (fp64)
__global__ void k_sturm(const double* __restrict__ dotWV, const float* __restrict__ betaSq,
                        const float* __restrict__ alphaIn, float* __restrict__ Lbuf){
  __shared__ double sa[LM+1], sb[LM+1];
  int lane = threadIdx.x;
  for (int i = lane; i <= LM; i += 64){
    if (i >= 1){
      sa[i] = dotWV[i];
      sb[i] = (i < LM) ? sqrt((double)betaSq[i]) : 0.0;
    }
  }
  __syncthreads();
  double phi = -1e300, plo = 1e300;
  for (int i = 1 + lane; i <= LM; i += 64){
    double r = (i > 1 ? sb[i-1] : 0.0) + (i < LM ? sb[i] : 0.0);
    phi = fmax(phi, sa[i] + r);
    plo = fmin(plo, sa[i] - r);
  }
  for (int o = 32; o > 0; o >>= 1){
    phi = fmax(phi, __shfl_down(phi, o));
    plo = fmin(plo, __shfl_down(plo, o));
  }
  double hi = __shfl(phi, 0), lo = __shfl(plo, 0);
  for (int round = 0; round < 6; round++){
    double x = lo + (hi - lo) * (double)(lane + 1) / 65.0;
    int cnt = 0;
    double dd = sa[1] - x;
    if (dd < 0) cnt++;
    for (int i = 2; i <= LM; i++){
      double off = sb[i-1];
      if (fabs(dd) < 1e-300) dd = -1e-300;
      dd = sa[i] - x - off*off/dd;
      if (dd < 0) cnt++;
    }
    unsigned long long bal = __ballot(cnt == LM);
    int p = (bal == 0ull) ? 64 : (__ffsll((unsigned long long)bal) - 1);
    double newhi = (p <= 63) ? lo + (hi - lo) * (double)(p + 1) / 65.0 : hi;
    double newlo = (p >= 1)  ? lo + (hi - lo) * (double)p / 65.0       : lo;
    hi = newhi; lo = newlo;
  }
  if (lane == 0){
    double L = 0.5*(lo + hi);
    Lbuf[0] = (float)(1.0 / L);
    Lbuf[1] = (float)(0.5 * (double)alphaIn[0] / L);
  }
}

// ---------------- FISTA ----------------

// iteration 0 elementwise (y0=0): sres = src*Y, delta-half update
__global__ __launch_bounds__(256) void k_A0(const float* __restrict__ Y, const float* __restrict__ src,
                                            float* __restrict__ yd, ushort_t* __restrict__ sresh,
                                            ushort_t* __restrict__ sresl, float* __restrict__ out,
                                            const float* __restrict__ Lbuf){
  int idx = blockIdx.x*256 + threadIdx.x;
  float invL = Lbuf[0], th = Lbuf[1];
  float y = Y[idx], s = src[idx];
  split2(s*y, &sresh[idx], &sresl[idx]);
  float xn = softt(y*invL, th);
  int b = idx >> 11, i = idx & 2047;
  out[(size_t)b*4096 + 2048 + i] = xn;
  yd[idx] = xn;   // c0 = 0 -> y1 = x1
}

// XCD swizzle for 512-block FISTA gemms: xcd = b&7 owns n-tiles xcd*4..+4
// (2MB W-tile working set, L2-resident), streams all 16 m-tiles.
__device__ __forceinline__ void swz512(int* m0, int* n0){
  const int b = blockIdx.x + (blockIdx.y << 5);
  const int xcd = b & 7, slot = b >> 3;          // slot in [0,64)
  *n0 = (((xcd << 2) + (slot >> 4)) << 6);
  *m0 = ((slot & 15) << 6);
}

// GEMM1: acc[b][i] = sum_k ym[b][k]*W[i][k]; fused res/sres/delta update
__global__ __launch_bounds__(256) void k_gemmA(
    const ushort_t* __restrict__ Wah, const ushort_t* __restrict__ Wal,
    const ushort_t* __restrict__ ymh, const ushort_t* __restrict__ yml,
    const float* __restrict__ Y, const float* __restrict__ src,
    float* __restrict__ yd, float* __restrict__ out,
    ushort_t* __restrict__ sresh, ushort_t* __restrict__ sresl,
    const float* __restrict__ Lbuf, float ck)
{
  f32x4 acc[2][2] = {};
  int m0, n0; swz512(&m0, &n0);
  gemm_core(ymh, yml, Wah, Wal, m0, n0, SDIM, acc);
  const float invL = Lbuf[0], th = Lbuf[1];
  const int tid = threadIdx.x, lane = tid & 63, wv = tid >> 6;
  const int wm = (wv >> 1) * 32, wn = (wv & 1) * 32;
  const int mm = lane & 15, quad = lane >> 4;
  #pragma unroll
  for (int tm = 0; tm < 2; tm++)
    #pragma unroll
    for (int tn = 0; tn < 2; tn++)
      #pragma unroll
      for (int i = 0; i < 4; i++){
        int brow = m0 + wm + tm*16 + quad*4 + i;
        int col  = n0 + wn + tn*16 + mm;
        int g = brow*SDIM + col;
        float a = acc[tm][tn][i];
        float s = src[g], ydv = yd[g];
        float res = Y[g] - s*a - ydv;
        split2(s*res, &sresh[g], &sresl[g]);
        float xn = softt(ydv + res*invL, th);
        int go = brow*4096 + 2048 + col;
        float xo = out[go];
        out[go] = xn;
        yd[g] = xn + ck*(xn - xo);
      }
}

// GEMM2: acc[b][j] = sum_i sres[b][i]*W[i][j]; fused theta update
template<bool FIRST>
__global__ __launch_bounds__(256) void k_gemmB(
    const ushort_t* __restrict__ Wbh, const ushort_t* __restrict__ Wbl,
    const ushort_t* __restrict__ sresh, const ushort_t* __restrict__ sresl,
    ushort_t* __restrict__ ymh, ushort_t* __restrict__ yml,
    float* __restrict__ out, const float* __restrict__ Lbuf, float ck)
{
  f32x4 acc[2][2] = {};
  int m0, n0; swz512(&m0, &n0);
  gemm_core(sresh, sresl, Wbh, Wbl, m0, n0, SDIM, acc);
  const float invL = Lbuf[0], th = Lbuf[1];
  const int tid = threadIdx.x, lane = tid & 63, wv = tid >> 6;
  const int wm = (wv >> 1) * 32, wn = (wv & 1) * 32;
  const int mm = lane & 15, quad = lane >> 4;
  #pragma unroll
  for (int tm = 0; tm < 2; tm++)
    #pragma unroll
    for (int tn = 0; tn < 2; tn++)
      #pragma unroll
      for (int i = 0; i < 4; i++){
        int brow = m0 + wm + tm*16 + quad*4 + i;
        int col  = n0 + wn + tn*16 + mm;
        int g = brow*SDIM + col;
        float a = acc[tm][tn][i];
        float ymv = FIRST ? 0.f : (bf2f(ymh[g]) + bf2f(yml[g]));
        float xn = softt(ymv + a*invL, th);
        int go = brow*4096 + col;
        float xo = FIRST ? 0.f : out[go];
        out[go] = xn;
        split2(xn + ck*(xn - xo), &ymh[g], &yml[g]);
      }
}

// ---------------- host ----------------

extern "C" void kernel_launch(void* const* d_in, const int* in_sizes, int n_in,
                              void* d_out, int out_size, void* d_ws, size_t ws_size,
                              hipStream_t stream) {
  const float* src   = (const float*)d_in[0];
  const float* Y     = (const float*)d_in[1];
  const float* W     = (const float*)d_in[2];
  const float* alpha = (const float*)d_in[3];
  float* out = (float*)d_out;
  float* ws  = (float*)d_ws;

  const size_t M1 = 1024*1024;
  float* Mmat = ws;                      // 4M floats (16MB)
  float* yd   = ws + 4*M1;               // 2M floats
  float* lanc = ws + 6*M1;
  float* w0      = lanc;                 // 2048
  float* w1      = lanc + SDIM;          // 2048
  float* vRing   = lanc + 2*SDIM;        // 3*2048
  double* dotWV  = (double*)(lanc + 5*SDIM);        // 128 doubles
  double* dotWW  = dotWV + 128;                     // 128 doubles
  float* betaSq  = lanc + 5*SDIM + 512;             // 128 floats
  float* Lbuf    = betaSq + 128;                    // 2
  ushort_t* u16 = (ushort_t*)(ws + 7*M1);
  ushort_t* Wah = u16;                   // 4M u16 each
  ushort_t* Wal = u16 + 4*M1;
  ushort_t* Wbh = u16 + 8*M1;
  ushort_t* Wbl = u16 + 12*M1;
  ushort_t* ymh = u16 + 16*M1;           // 2M u16 each
  ushort_t* yml = u16 + 18*M1;
  ushort_t* sresh = u16 + 20*M1;
  ushort_t* sresl = u16 + 22*M1;

  // ---- split W (and W^T) into bf16 hi/lo ----
  k_split<<<dim3(64,64), 256, 0, stream>>>(W, Wah, Wal, Wbh, Wbl);
  // ---- M = W W^T for Lanczos ----
  k_gemmM<<<dim3(32,32), 256, 0, stream>>>(Wah, Wal, Mmat);

  // ---- Lanczos for L = lambda_max: one kernel per step ----
  float* wb[2] = { w0, w1 };
  k_init<<<1, 256, 0, stream>>>(vRing, dotWV, dotWW, betaSq);
  for (int s = 1; s <= LM; s++){
    k_lstep<<<512, 256, 0, stream>>>(Mmat, wb[(s+1)&1], wb[s&1], vRing, dotWV, dotWW, betaSq, s);
  }
  k_sturm<<<1, 64, 0, stream>>>(dotWV, betaSq, alpha, Lbuf);

  // ---- momentum coefficients (data independent) ----
  double t = 1.0;
  float ckv[NITER];
  for (int k = 0; k < NITER; k++){
    double tn = 0.5*(1.0 + sqrt(1.0 + 4.0*t*t));
    ckv[k] = (float)((t - 1.0)/tn);
    t = tn;
  }

  // ---- FISTA ----
  k_A0<<<(BATCH*SDIM)/256, 256, 0, stream>>>(Y, src, yd, sresh, sresl, out, Lbuf);
  k_gemmB<true><<<dim3(32,16), 256, 0, stream>>>(Wbh, Wbl, sresh, sresl, ymh, yml, out, Lbuf, ckv[0]);
  for (int k = 1; k < NITER; k++){
    k_gemmA<<<dim3(32,16), 256, 0, stream>>>(Wah, Wal, ymh, yml, Y, src, yd, out, sresh, sresl, Lbuf, ckv[k]);
    k_gemmB<false><<<dim3(32,16), 256, 0, stream>>>(Wbh, Wbl, sresh, sresl, ymh, yml, out, Lbuf, ckv[k]);
  }
  (void)in_sizes; (void)n_in; (void)out_size; (void)ws_size;
}

// Round 9
// 1853.378 us; speedup vs baseline: 1.3872x; 1.0291x over previous
//
#include <hip/hip_runtime.h>
#include <math.h>

#define SDIM 2048
#define BATCH 1024
#define NITER 16
#define LM 48   // Lanczos steps

typedef unsigned short ushort_t;
typedef __attribute__((ext_vector_type(8))) short bf16x8;
typedef __attribute__((ext_vector_type(4))) float f32x4;

#define MFMA(a,b,c) __builtin_amdgcn_mfma_f32_16x16x32_bf16((a),(b),(c),0,0,0)

__device__ __forceinline__ float softt(float v, float th){
  return copysignf(fmaxf(fabsf(v) - th, 0.0f), v);
}

__device__ __forceinline__ float bf2f(ushort_t h){
  return __uint_as_float(((unsigned)h) << 16);
}

// RTNE float -> bf16 hi + bf16 lo split
__device__ __forceinline__ void split2(float x, ushort_t* h, ushort_t* l){
  unsigned u = __float_as_uint(x);
  unsigned hh = (u + 0x7FFFu + ((u >> 16) & 1u)) >> 16;
  float hf = __uint_as_float(hh << 16);
  float r = x - hf;                       // exact
  unsigned v = __float_as_uint(r);
  unsigned ll = (v + 0x7FFFu + ((v >> 16) & 1u)) >> 16;
  *h = (ushort_t)hh; *l = (ushort_t)ll;
}

// async 16B global -> LDS
__device__ __forceinline__ void cp16(const ushort_t* g, ushort_t* l){
  __builtin_amdgcn_global_load_lds(
      (const __attribute__((address_space(1))) unsigned int*)g,
      (__attribute__((address_space(3))) unsigned int*)l, 16, 0, 0);
}

// ---------------- MFMA GEMM core (64x64, BK=64, 4 waves, single buffer,
// register-prefetch K-loop) ----------------
// Per kt: sync(A) [drains tile-kt staging, issued one compute phase earlier]
// -> ds_read ALL 16 frags to regs -> sync(B) [cheap lgkmcnt] -> cp16 tile kt+1
// into the SAME buffer (safe: B guarantees reads done; DMA stays after reads
// in program order) -> 48 MFMAs on registers.
// LDS layout (proven 0 conflicts): chunk (row r, kchunk kp) at ushort offset
// r*64 + (kp^(r&7))*8; staging lane-linear. 32KB LDS -> 2 blocks/CU.
// History: dbuf variants SLOWER (r4 conflicts, r7 DMA-before-reads poisons
// scheduling); this order is the one that hides the vmcnt drain.
__device__ __forceinline__ void gemm_core(const ushort_t* __restrict__ Ah, const ushort_t* __restrict__ Al,
                                          const ushort_t* __restrict__ Bh, const ushort_t* __restrict__ Bl,
                                          int m0, int n0, int K, f32x4 acc[2][2])
{
  __shared__ ushort_t lAh[64*64], lAl[64*64], lBh[64*64], lBl[64*64];
  const int tid = threadIdx.x;
  const int rr = tid >> 3;
  const int kp = (tid & 7) ^ (rr & 7);
  const size_t strA = (size_t)32 * K;
  const ushort_t* gAh = Ah + (size_t)(m0 + rr) * K + kp * 8;
  const ushort_t* gAl = Al + (size_t)(m0 + rr) * K + kp * 8;
  const ushort_t* gBh = Bh + (size_t)(n0 + rr) * K + kp * 8;
  const ushort_t* gBl = Bl + (size_t)(n0 + rr) * K + kp * 8;
  ushort_t* dA0 = &lAh[tid * 8];      ushort_t* dA1 = &lAh[(tid + 256) * 8];
  ushort_t* dAl0 = &lAl[tid * 8];     ushort_t* dAl1 = &lAl[(tid + 256) * 8];
  ushort_t* dB0 = &lBh[tid * 8];      ushort_t* dB1 = &lBh[(tid + 256) * 8];
  ushort_t* dBl0 = &lBl[tid * 8];     ushort_t* dBl1 = &lBl[(tid + 256) * 8];

  const int lane = tid & 63, wv = tid >> 6;
  const int wm = (wv >> 1) * 32, wn = (wv & 1) * 32;
  const int mm = lane & 15, quad = lane >> 4;
  const int ra0 = wm + mm, ra1 = wm + 16 + mm;
  const int rb0 = wn + mm, rb1 = wn + 16 + mm;
  // frag read offsets for u=0,1 (precomputed)
  int oa0[2], oa1[2], ob0[2], ob1[2];
  #pragma unroll
  for (int u = 0; u < 2; u++){
    oa0[u] = ra0*64 + (((u*4 + quad) ^ (ra0 & 7)) << 3);
    oa1[u] = ra1*64 + (((u*4 + quad) ^ (ra1 & 7)) << 3);
    ob0[u] = rb0*64 + (((u*4 + quad) ^ (rb0 & 7)) << 3);
    ob1[u] = rb1*64 + (((u*4 + quad) ^ (rb1 & 7)) << 3);
  }

  const int nk = K / 64;
  // prologue: stage tile 0
  cp16(gAh, dA0); cp16(gAh + strA, dA1);
  cp16(gAl, dAl0); cp16(gAl + strA, dAl1);
  cp16(gBh, dB0); cp16(gBh + strA, dB1);
  cp16(gBl, dBl0); cp16(gBl + strA, dBl1);
  gAh += 64; gAl += 64; gBh += 64; gBl += 64;

  for (int kt = 0; kt < nk; kt++){
    __syncthreads();   // (A) tile kt staged -- drain issued one phase ago
    bf16x8 ah0[2], ah1[2], al0[2], al1[2], bh0[2], bh1[2], bl0[2], bl1[2];
    #pragma unroll
    for (int u = 0; u < 2; u++){
      ah0[u] = *(const bf16x8*)&lAh[oa0[u]];
      ah1[u] = *(const bf16x8*)&lAh[oa1[u]];
      al0[u] = *(const bf16x8*)&lAl[oa0[u]];
      al1[u] = *(const bf16x8*)&lAl[oa1[u]];
      bh0[u] = *(const bf16x8*)&lBh[ob0[u]];
      bh1[u] = *(const bf16x8*)&lBh[ob1[u]];
      bl0[u] = *(const bf16x8*)&lBl[ob0[u]];
      bl1[u] = *(const bf16x8*)&lBl[ob1[u]];
    }
    __syncthreads();   // (B) all reads done -> LDS free for overwrite
    if (kt + 1 < nk){
      cp16(gAh, dA0); cp16(gAh + strA, dA1);
      cp16(gAl, dAl0); cp16(gAl + strA, dAl1);
      cp16(gBh, dB0); cp16(gBh + strA, dB1);
      cp16(gBl, dBl0); cp16(gBl + strA, dBl1);
      gAh += 64; gAl += 64; gBh += 64; gBl += 64;
    }
    #pragma unroll
    for (int u = 0; u < 2; u++){
      acc[0][0] = MFMA(ah0[u], bh0[u], acc[0][0]);
      acc[0][0] = MFMA(ah0[u], bl0[u], acc[0][0]);
      acc[0][0] = MFMA(al0[u], bh0[u], acc[0][0]);
      acc[0][1] = MFMA(ah0[u], bh1[u], acc[0][1]);
      acc[0][1] = MFMA(ah0[u], bl1[u], acc[0][1]);
      acc[0][1] = MFMA(al0[u], bh1[u], acc[0][1]);
      acc[1][0] = MFMA(ah1[u], bh0[u], acc[1][0]);
      acc[1][0] = MFMA(ah1[u], bl0[u], acc[1][0]);
      acc[1][0] = MFMA(al1[u], bh0[u], acc[1][0]);
      acc[1][1] = MFMA(ah1[u], bh1[u], acc[1][1]);
      acc[1][1] = MFMA(ah1[u], bl1[u], acc[1][1]);
      acc[1][1] = MFMA(al1[u], bh1[u], acc[1][1]);
    }
  }
}

// ---------------- W split / transpose-split ----------------
__global__ __launch_bounds__(256) void k_split(const float* __restrict__ W,
                                               ushort_t* __restrict__ Wah, ushort_t* __restrict__ Wal,
                                               ushort_t* __restrict__ Wbh, ushort_t* __restrict__ Wbl){
  __shared__ float t[32][33];
  const int i0 = blockIdx.y * 32, j0 = blockIdx.x * 32;
  const int r = threadIdx.x >> 3, c = (threadIdx.x & 7) * 4;
  const float4 v = *(const float4*)&W[(size_t)(i0 + r) * SDIM + j0 + c];
  float vv[4] = {v.x, v.y, v.z, v.w};
  ushort_t h[4], l[4];
  #pragma unroll
  for (int q = 0; q < 4; q++){ split2(vv[q], &h[q], &l[q]); t[r][c+q] = vv[q]; }
  *(ushort4*)&Wah[(size_t)(i0 + r) * SDIM + j0 + c] = make_ushort4(h[0],h[1],h[2],h[3]);
  *(ushort4*)&Wal[(size_t)(i0 + r) * SDIM + j0 + c] = make_ushort4(l[0],l[1],l[2],l[3]);
  __syncthreads();
  #pragma unroll
  for (int q = 0; q < 4; q++) split2(t[c+q][r], &h[q], &l[q]);
  *(ushort4*)&Wbh[(size_t)(j0 + r) * SDIM + i0 + c] = make_ushort4(h[0],h[1],h[2],h[3]);
  *(ushort4*)&Wbl[(size_t)(j0 + r) * SDIM + i0 + c] = make_ushort4(l[0],l[1],l[2],l[3]);
}

// M = W * W^T (same nonzero spectrum as W^T W). XCD-swizzled grid (1024 blocks).
__global__ __launch_bounds__(256) void k_gemmM(const ushort_t* __restrict__ Wah, const ushort_t* __restrict__ Wal,
                                               float* __restrict__ Mmat){
  const int b = blockIdx.x + (blockIdx.y << 5);
  const int xcd = b & 7, slot = b >> 3;          // slot in [0,128)
  const int n0 = (((xcd << 2) + (slot >> 5)) << 6);
  const int m0 = ((slot & 31) << 6);
  f32x4 acc[2][2] = {};
  gemm_core(Wah, Wal, Wah, Wal, m0, n0, SDIM, acc);
  const int tid = threadIdx.x, lane = tid & 63, wv = tid >> 6;
  const int wm = (wv >> 1) * 32, wn = (wv & 1) * 32;
  const int mm = lane & 15, quad = lane >> 4;
  #pragma unroll
  for (int tm = 0; tm < 2; tm++)
    #pragma unroll
    for (int tn = 0; tn < 2; tn++)
      #pragma unroll
      for (int i = 0; i < 4; i++){
        int row = m0 + wm + tm*16 + quad*4 + i;
        int col = n0 + wn + tn*16 + mm;
        Mmat[(size_t)row * SDIM + col] = acc[tm][tn][i];
      }
}

// ---------------- Lanczos on M: one kernel per step ----------------
__global__ __launch_bounds__(256) void k_init(float* __restrict__ vRing,
                                              double* __restrict__ dotWV, double* __restrict__ dotWW,
                                              float* __restrict__ betaSq){
  __shared__ float red[256];
  int t = threadIdx.x;
  float vals[8];
  float s = 0.f;
  #pragma unroll
  for (int p = 0; p < 8; p++){
    int j = p*256 + t;
    unsigned h = (unsigned)j * 2654435761u;
    h ^= h >> 16; h *= 2246822519u; h ^= h >> 13;
    float r = (float)(h & 0xFFFFFFu) / 16777216.0f - 0.5f;
    vals[p] = r; s += r*r;
  }
  red[t] = s; __syncthreads();
  for (int o = 128; o > 0; o >>= 1){ if (t < o) red[t] += red[t+o]; __syncthreads(); }
  float inv = rsqrtf(red[0]);
  #pragma unroll
  for (int p = 0; p < 8; p++){
    int j = p*256 + t;
    vRing[SDIM + j] = vals[p]*inv;   // slot 1 = v_1
    vRing[j] = 0.f;                  // slot 0
    vRing[2*SDIM + j] = 0.f;         // slot 2
  }
  if (t < LM+2){ dotWV[t] = 0.0; dotWW[t] = 0.0; betaSq[t] = 0.f; }
}

// step s: reconstruct v_s from w_{s-1} (redundant per block), then 4 rows of M v_s.
// beta^2_{s-1} = ||w||^2 - alpha^2 - beta^2_{s-2}  (fp64 scalar chain)
__global__ __launch_bounds__(256) void k_lstep(const float* __restrict__ M,
    const float* __restrict__ wOld, float* __restrict__ wNew,
    float* __restrict__ vRing, double* __restrict__ dotWV, double* __restrict__ dotWW,
    float* __restrict__ betaSq, int s){
  __shared__ float vs[SDIM];
  __shared__ double pAl[4], pWw[4];
  const int tid = threadIdx.x, bid = blockIdx.x;
  if (s == 1){
    const float* v1 = vRing + SDIM;
    for (int j = tid; j < SDIM; j += 256) vs[j] = v1[j];
  } else {
    const double a  = dotWV[s-1];
    const double ww = dotWW[s-1];
    const float bpSq = betaSq[s-2];
    float bsq = (float)(ww - a*a - (double)bpSq);
    bsq = fmaxf(bsq, 1e-20f);
    const float beta = sqrtf(bsq), invb = 1.0f/beta;
    const float alpha = (float)a, bprev = sqrtf(bpSq);
    const float* vm1 = vRing + ((s-1)%3)*SDIM;
    const float* vm2 = vRing + ((s-2)%3)*SDIM;
    float* vdst = vRing + (s%3)*SDIM;
    for (int j = tid; j < SDIM; j += 256){
      float val = (wOld[j] - alpha*vm1[j] - bprev*vm2[j]) * invb;
      vs[j] = val;
      if (bid == 0) vdst[j] = val;
    }
    if (bid == 0 && tid == 0) betaSq[s-1] = bsq;
  }
  __syncthreads();
  const int wv = tid >> 6, lane = tid & 63;
  const int row = bid*4 + wv;
  const float4* Mr = (const float4*)(M + (size_t)row * SDIM);
  const float4* v4 = (const float4*)vs;
  float acc = 0.f;
  #pragma unroll
  for (int p = 0; p < 8; p++){
    int j4 = p*64 + lane;
    float4 m = Mr[j4], v = v4[j4];
    acc += m.x*v.x + m.y*v.y + m.z*v.z + m.w*v.w;
  }
  #pragma unroll
  for (int o = 32; o > 0; o >>= 1) acc += __shfl_down(acc, o);
  if (lane == 0){
    wNew[row] = acc;
    pAl[wv] = (double)acc * (double)vs[row];
    pWw[wv] = (double)acc * (double)acc;
  }
  __syncthreads();
  if (tid == 0){
    atomicAdd(&dotWV[s], pAl[0]+pAl[1]+pAl[2]+pAl[3]);
    atomicAdd(&dotWW[s], pWw[0]+pWw[1]+pWw[2]+pWw[3]);
  }
}

// lambda_max of tridiagonal via lane-parallel Sturm bisection (fp64)
__global__ void k_sturm(const double* __restrict__ dotWV, const float* __restrict__ betaSq,
                        const float* __restrict__ alphaIn, float* __restrict__ Lbuf){
  __shared__ double sa[LM+1], sb[LM+1];
  int lane = threadIdx.x;
  for (int i = lane; i <= LM; i += 64){
    if (i >= 1){
      sa[i] = dotWV[i];
      sb[i] = (i < LM) ? sqrt((double)betaSq[i]) : 0.0;
    }
  }
  __syncthreads();
  double phi = -1e300, plo = 1e300;
  for (int i = 1 + lane; i <= LM; i += 64){
    double r = (i > 1 ? sb[i-1] : 0.0) + (i < LM ? sb[i] : 0.0);
    phi = fmax(phi, sa[i] + r);
    plo = fmin(plo, sa[i] - r);
  }
  for (int o = 32; o > 0; o >>= 1){
    phi = fmax(phi, __shfl_down(phi, o));
    plo = fmin(plo, __shfl_down(plo, o));
  }
  double hi = __shfl(phi, 0), lo = __shfl(plo, 0);
  for (int round = 0; round < 6; round++){
    double x = lo + (hi - lo) * (double)(lane + 1) / 65.0;
    int cnt = 0;
    double dd = sa[1] - x;
    if (dd < 0) cnt++;
    for (int i = 2; i <= LM; i++){
      double off = sb[i-1];
      if (fabs(dd) < 1e-300) dd = -1e-300;
      dd = sa[i] - x - off*off/dd;
      if (dd < 0) cnt++;
    }
    unsigned long long bal = __ballot(cnt == LM);
    int p = (bal == 0ull) ? 64 : (__ffsll((unsigned long long)bal) - 1);
    double newhi = (p <= 63) ? lo + (hi - lo) * (double)(p + 1) / 65.0 : hi;
    double newlo = (p >= 1)  ? lo + (hi - lo) * (double)p / 65.0       : lo;
    hi = newhi; lo = newlo;
  }
  if (lane == 0){
    double L = 0.5*(lo + hi);
    Lbuf[0] = (float)(1.0 / L);
    Lbuf[1] = (float)(0.5 * (double)alphaIn[0] / L);
  }
}

// ---------------- FISTA ----------------

// iteration 0 elementwise (y0=0): sres = src*Y, delta-half update
__global__ __launch_bounds__(256) void k_A0(const float* __restrict__ Y, const float* __restrict__ src,
                                            float* __restrict__ yd, ushort_t* __restrict__ sresh,
                                            ushort_t* __restrict__ sresl, float* __restrict__ out,
                                            const float* __restrict__ Lbuf){
  int idx = blockIdx.x*256 + threadIdx.x;
  float invL = Lbuf[0], th = Lbuf[1];
  float y = Y[idx], s = src[idx];
  split2(s*y, &sresh[idx], &sresl[idx]);
  float xn = softt(y*invL, th);
  int b = idx >> 11, i = idx & 2047;
  out[(size_t)b*4096 + 2048 + i] = xn;
  yd[idx] = xn;   // c0 = 0 -> y1 = x1
}

// XCD swizzle for 512-block FISTA gemms: xcd = b&7 owns n-tiles xcd*4..+4,
// streams all 16 m-tiles.
__device__ __forceinline__ void swz512(int* m0, int* n0){
  const int b = blockIdx.x + (blockIdx.y << 5);
  const int xcd = b & 7, slot = b >> 3;          // slot in [0,64)
  *n0 = (((xcd << 2) + (slot >> 4)) << 6);
  *m0 = ((slot & 15) << 6);
}

// GEMM1: acc[b][i] = sum_k ym[b][k]*W[i][k]; fused res/sres/delta update
__global__ __launch_bounds__(256) void k_gemmA(
    const ushort_t* __restrict__ Wah, const ushort_t* __restrict__ Wal,
    const ushort_t* __restrict__ ymh, const ushort_t* __restrict__ yml,
    const float* __restrict__ Y, const float* __restrict__ src,
    float* __restrict__ yd, float* __restrict__ out,
    ushort_t* __restrict__ sresh, ushort_t* __restrict__ sresl,
    const float* __restrict__ Lbuf, float ck)
{
  f32x4 acc[2][2] = {};
  int m0, n0; swz512(&m0, &n0);
  gemm_core(ymh, yml, Wah, Wal, m0, n0, SDIM, acc);
  const float invL = Lbuf[0], th = Lbuf[1];
  const int tid = threadIdx.x, lane = tid & 63, wv = tid >> 6;
  const int wm = (wv >> 1) * 32, wn = (wv & 1) * 32;
  const int mm = lane & 15, quad = lane >> 4;
  #pragma unroll
  for (int tm = 0; tm < 2; tm++)
    #pragma unroll
    for (int tn = 0; tn < 2; tn++)
      #pragma unroll
      for (int i = 0; i < 4; i++){
        int brow = m0 + wm + tm*16 + quad*4 + i;
        int col  = n0 + wn + tn*16 + mm;
        int g = brow*SDIM + col;
        float a = acc[tm][tn][i];
        float s = src[g], ydv = yd[g];
        float res = Y[g] - s*a - ydv;
        split2(s*res, &sresh[g], &sresl[g]);
        float xn = softt(ydv + res*invL, th);
        int go = brow*4096 + 2048 + col;
        float xo = out[go];
        out[go] = xn;
        yd[g] = xn + ck*(xn - xo);
      }
}

// GEMM2: acc[b][j] = sum_i sres[b][i]*W[i][j]; fused theta update
template<bool FIRST>
__global__ __launch_bounds__(256) void k_gemmB(
    const ushort_t* __restrict__ Wbh, const ushort_t* __restrict__ Wbl,
    const ushort_t* __restrict__ sresh, const ushort_t* __restrict__ sresl,
    ushort_t* __restrict__ ymh, ushort_t* __restrict__ yml,
    float* __restrict__ out, const float* __restrict__ Lbuf, float ck)
{
  f32x4 acc[2][2] = {};
  int m0, n0; swz512(&m0, &n0);
  gemm_core(sresh, sresl, Wbh, Wbl, m0, n0, SDIM, acc);
  const float invL = Lbuf[0], th = Lbuf[1];
  const int tid = threadIdx.x, lane = tid & 63, wv = tid >> 6;
  const int wm = (wv >> 1) * 32, wn = (wv & 1) * 32;
  const int mm = lane & 15, quad = lane >> 4;
  #pragma unroll
  for (int tm = 0; tm < 2; tm++)
    #pragma unroll
    for (int tn = 0; tn < 2; tn++)
      #pragma unroll
      for (int i = 0; i < 4; i++){
        int brow = m0 + wm + tm*16 + quad*4 + i;
        int col  = n0 + wn + tn*16 + mm;
        int g = brow*SDIM + col;
        float a = acc[tm][tn][i];
        float ymv = FIRST ? 0.f : (bf2f(ymh[g]) + bf2f(yml[g]));
        float xn = softt(ymv + a*invL, th);
        int go = brow*4096 + col;
        float xo = FIRST ? 0.f : out[go];
        out[go] = xn;
        split2(xn + ck*(xn - xo), &ymh[g], &yml[g]);
      }
}

// ---------------- host ----------------

extern "C" void kernel_launch(void* const* d_in, const int* in_sizes, int n_in,
                              void* d_out, int out_size, void* d_ws, size_t ws_size,
                              hipStream_t stream) {
  const float* src   = (const float*)d_in[0];
  const float* Y     = (const float*)d_in[1];
  const float* W     = (const float*)d_in[2];
  const float* alpha = (const float*)d_in[3];
  float* out = (float*)d_out;
  float* ws  = (float*)d_ws;

  const size_t M1 = 1024*1024;
  float* Mmat = ws;                      // 4M floats (16MB)
  float* yd   = ws + 4*M1;               // 2M floats
  float* lanc = ws + 6*M1;
  float* w0      = lanc;                 // 2048
  float* w1      = lanc + SDIM;          // 2048
  float* vRing   = lanc + 2*SDIM;        // 3*2048
  double* dotWV  = (double*)(lanc + 5*SDIM);        // 128 doubles
  double* dotWW  = dotWV + 128;                     // 128 doubles
  float* betaSq  = lanc + 5*SDIM + 512;             // 128 floats
  float* Lbuf    = betaSq + 128;                    // 2
  ushort_t* u16 = (ushort_t*)(ws + 7*M1);
  ushort_t* Wah = u16;                   // 4M u16 each
  ushort_t* Wal = u16 + 4*M1;
  ushort_t* Wbh = u16 + 8*M1;
  ushort_t* Wbl = u16 + 12*M1;
  ushort_t* ymh = u16 + 16*M1;           // 2M u16 each
  ushort_t* yml = u16 + 18*M1;
  ushort_t* sresh = u16 + 20*M1;
  ushort_t* sresl = u16 + 22*M1;

  // ---- split W (and W^T) into bf16 hi/lo ----
  k_split<<<dim3(64,64), 256, 0, stream>>>(W, Wah, Wal, Wbh, Wbl);
  // ---- M = W W^T for Lanczos ----
  k_gemmM<<<dim3(32,32), 256, 0, stream>>>(Wah, Wal, Mmat);

  // ---- Lanczos for L = lambda_max: one kernel per step ----
  float* wb[2] = { w0, w1 };
  k_init<<<1, 256, 0, stream>>>(vRing, dotWV, dotWW, betaSq);
  for (int s = 1; s <= LM; s++){
    k_lstep<<<512, 256, 0, stream>>>(Mmat, wb[(s+1)&1], wb[s&1], vRing, dotWV, dotWW, betaSq, s);
  }
  k_sturm<<<1, 64, 0, stream>>>(dotWV, betaSq, alpha, Lbuf);

  // ---- momentum coefficients (data independent) ----
  double t = 1.0;
  float ckv[NITER];
  for (int k = 0; k < NITER; k++){
    double tn = 0.5*(1.0 + sqrt(1.0 + 4.0*t*t));
    ckv[k] = (float)((t - 1.0)/tn);
    t = tn;
  }

  // ---- FISTA ----
  k_A0<<<(BATCH*SDIM)/256, 256, 0, stream>>>(Y, src, yd, sresh, sresl, out, Lbuf);
  k_gemmB<true><<<dim3(32,16), 256, 0, stream>>>(Wbh, Wbl, sresh, sresl, ymh, yml, out, Lbuf, ckv[0]);
  for (int k = 1; k < NITER; k++){
    k_gemmA<<<dim3(32,16), 256, 0, stream>>>(Wah, Wal, ymh, yml, Y, src, yd, out, sresh, sresl, Lbuf, ckv[k]);
    k_gemmB<false><<<dim3(32,16), 256, 0, stream>>>(Wbh, Wbl, sresh, sresl, ymh, yml, out, Lbuf, ckv[k]);
  }
  (void)in_sizes; (void)n_in; (void)out_size; (void)ws_size;
}

// Round 10
// 1703.127 us; speedup vs baseline: 1.5096x; 1.0882x over previous
//
#include <hip/hip_runtime.h>
#include <math.h>

#define SDIM 2048
#define BATCH 1024
#define NITER 16
#define LM 40   // Lanczos steps

typedef unsigned short ushort_t;
typedef __attribute__((ext_vector_type(8))) short bf16x8;
typedef __attribute__((ext_vector_type(4))) float f32x4;

#define MFMA(a,b,c) __builtin_amdgcn_mfma_f32_16x16x32_bf16((a),(b),(c),0,0,0)

__device__ __forceinline__ float softt(float v, float th){
  return copysignf(fmaxf(fabsf(v) - th, 0.0f), v);
}

__device__ __forceinline__ float bf2f(ushort_t h){
  return __uint_as_float(((unsigned)h) << 16);
}

// RTNE float -> bf16 hi + bf16 lo split
__device__ __forceinline__ void split2(float x, ushort_t* h, ushort_t* l){
  unsigned u = __float_as_uint(x);
  unsigned hh = (u + 0x7FFFu + ((u >> 16) & 1u)) >> 16;
  float hf = __uint_as_float(hh << 16);
  float r = x - hf;                       // exact
  unsigned v = __float_as_uint(r);
  unsigned ll = (v + 0x7FFFu + ((v >> 16) & 1u)) >> 16;
  *h = (ushort_t)hh; *l = (ushort_t)ll;
}

// async 16B global -> LDS
__device__ __forceinline__ void cp16(const ushort_t* g, ushort_t* l){
  __builtin_amdgcn_global_load_lds(
      (const __attribute__((address_space(1))) unsigned int*)g,
      (__attribute__((address_space(3))) unsigned int*)l, 16, 0, 0);
}

// ---------------- MFMA GEMM core (r9: 64x64, BK=64, 4 waves, single buffer,
// register-prefetch K-loop). smem: 16384 ushorts (32KB), caller-owned. ----------------
__device__ __forceinline__ void gemm_core(ushort_t* __restrict__ sm,
                                          const ushort_t* __restrict__ Ah, const ushort_t* __restrict__ Al,
                                          const ushort_t* __restrict__ Bh, const ushort_t* __restrict__ Bl,
                                          int m0, int n0, int K, f32x4 acc[2][2])
{
  ushort_t* lAh = sm;
  ushort_t* lAl = sm + 4096;
  ushort_t* lBh = sm + 8192;
  ushort_t* lBl = sm + 12288;
  const int tid = threadIdx.x;
  const int rr = tid >> 3;
  const int kp = (tid & 7) ^ (rr & 7);
  const size_t strA = (size_t)32 * K;
  const ushort_t* gAh = Ah + (size_t)(m0 + rr) * K + kp * 8;
  const ushort_t* gAl = Al + (size_t)(m0 + rr) * K + kp * 8;
  const ushort_t* gBh = Bh + (size_t)(n0 + rr) * K + kp * 8;
  const ushort_t* gBl = Bl + (size_t)(n0 + rr) * K + kp * 8;
  ushort_t* dA0 = &lAh[tid * 8];      ushort_t* dA1 = &lAh[(tid + 256) * 8];
  ushort_t* dAl0 = &lAl[tid * 8];     ushort_t* dAl1 = &lAl[(tid + 256) * 8];
  ushort_t* dB0 = &lBh[tid * 8];      ushort_t* dB1 = &lBh[(tid + 256) * 8];
  ushort_t* dBl0 = &lBl[tid * 8];     ushort_t* dBl1 = &lBl[(tid + 256) * 8];

  const int lane = tid & 63, wv = tid >> 6;
  const int wm = (wv >> 1) * 32, wn = (wv & 1) * 32;
  const int mm = lane & 15, quad = lane >> 4;
  const int ra0 = wm + mm, ra1 = wm + 16 + mm;
  const int rb0 = wn + mm, rb1 = wn + 16 + mm;
  int oa0[2], oa1[2], ob0[2], ob1[2];
  #pragma unroll
  for (int u = 0; u < 2; u++){
    oa0[u] = ra0*64 + (((u*4 + quad) ^ (ra0 & 7)) << 3);
    oa1[u] = ra1*64 + (((u*4 + quad) ^ (ra1 & 7)) << 3);
    ob0[u] = rb0*64 + (((u*4 + quad) ^ (rb0 & 7)) << 3);
    ob1[u] = rb1*64 + (((u*4 + quad) ^ (rb1 & 7)) << 3);
  }

  const int nk = K / 64;
  cp16(gAh, dA0); cp16(gAh + strA, dA1);
  cp16(gAl, dAl0); cp16(gAl + strA, dAl1);
  cp16(gBh, dB0); cp16(gBh + strA, dB1);
  cp16(gBl, dBl0); cp16(gBl + strA, dBl1);
  gAh += 64; gAl += 64; gBh += 64; gBl += 64;

  for (int kt = 0; kt < nk; kt++){
    __syncthreads();   // (A) tile kt staged -- drain issued one phase ago
    bf16x8 ah0[2], ah1[2], al0[2], al1[2], bh0[2], bh1[2], bl0[2], bl1[2];
    #pragma unroll
    for (int u = 0; u < 2; u++){
      ah0[u] = *(const bf16x8*)&lAh[oa0[u]];
      ah1[u] = *(const bf16x8*)&lAh[oa1[u]];
      al0[u] = *(const bf16x8*)&lAl[oa0[u]];
      al1[u] = *(const bf16x8*)&lAl[oa1[u]];
      bh0[u] = *(const bf16x8*)&lBh[ob0[u]];
      bh1[u] = *(const bf16x8*)&lBh[ob1[u]];
      bl0[u] = *(const bf16x8*)&lBl[ob0[u]];
      bl1[u] = *(const bf16x8*)&lBl[ob1[u]];
    }
    __syncthreads();   // (B) all reads done -> LDS free for overwrite
    if (kt + 1 < nk){
      cp16(gAh, dA0); cp16(gAh + strA, dA1);
      cp16(gAl, dAl0); cp16(gAl + strA, dAl1);
      cp16(gBh, dB0); cp16(gBh + strA, dB1);
      cp16(gBl, dBl0); cp16(gBl + strA, dBl1);
      gAh += 64; gAl += 64; gBh += 64; gBl += 64;
    }
    #pragma unroll
    for (int u = 0; u < 2; u++){
      acc[0][0] = MFMA(ah0[u], bh0[u], acc[0][0]);
      acc[0][0] = MFMA(ah0[u], bl0[u], acc[0][0]);
      acc[0][0] = MFMA(al0[u], bh0[u], acc[0][0]);
      acc[0][1] = MFMA(ah0[u], bh1[u], acc[0][1]);
      acc[0][1] = MFMA(ah0[u], bl1[u], acc[0][1]);
      acc[0][1] = MFMA(al0[u], bh1[u], acc[0][1]);
      acc[1][0] = MFMA(ah1[u], bh0[u], acc[1][0]);
      acc[1][0] = MFMA(ah1[u], bl0[u], acc[1][0]);
      acc[1][0] = MFMA(al1[u], bh0[u], acc[1][0]);
      acc[1][1] = MFMA(ah1[u], bh1[u], acc[1][1]);
      acc[1][1] = MFMA(ah1[u], bl1[u], acc[1][1]);
      acc[1][1] = MFMA(al1[u], bh1[u], acc[1][1]);
    }
  }
}

// Dump acc to LDS fp32 tile (stride 65, conflict-free) for coalesced epilogue.
// After the K-loop no wave touches LDS, so writes need no leading barrier.
__device__ __forceinline__ void acc_to_tile(ushort_t* sm, f32x4 acc[2][2]){
  float* tile = (float*)sm;
  const int tid = threadIdx.x, lane = tid & 63, wv = tid >> 6;
  const int wm = (wv >> 1) * 32, wn = (wv & 1) * 32;
  const int mm = lane & 15, quad = lane >> 4;
  #pragma unroll
  for (int tm = 0; tm < 2; tm++)
    #pragma unroll
    for (int tn = 0; tn < 2; tn++)
      #pragma unroll
      for (int i = 0; i < 4; i++)
        tile[(wm + tm*16 + quad*4 + i)*65 + wn + tn*16 + mm] = acc[tm][tn][i];
  __syncthreads();
}

// Coalesced epilogue mapping: wave w covers rows w*16..+15; per j (0..3):
// row = w*16 + j*4 + (lane>>4), cols 4*(lane&15)..+4 -> 16 lanes x 16B = 256B
// contiguous per row for every global access.
#define EPILOGUE_FOR(rowvar, c4var) \
  const int tid = threadIdx.x, lane = tid & 63, wv = tid >> 6; \
  const int r4 = lane >> 4; \
  const int c4var = (lane & 15) * 4; \
  for (int j = 0; j < 4; j++){ \
    const int rowvar = wv*16 + j*4 + r4;

// ---------------- W split / transpose-split ----------------
__global__ __launch_bounds__(256) void k_split(const float* __restrict__ W,
                                               ushort_t* __restrict__ Wah, ushort_t* __restrict__ Wal,
                                               ushort_t* __restrict__ Wbh, ushort_t* __restrict__ Wbl){
  __shared__ float t[32][33];
  const int i0 = blockIdx.y * 32, j0 = blockIdx.x * 32;
  const int r = threadIdx.x >> 3, c = (threadIdx.x & 7) * 4;
  const float4 v = *(const float4*)&W[(size_t)(i0 + r) * SDIM + j0 + c];
  float vv[4] = {v.x, v.y, v.z, v.w};
  ushort_t h[4], l[4];
  #pragma unroll
  for (int q = 0; q < 4; q++){ split2(vv[q], &h[q], &l[q]); t[r][c+q] = vv[q]; }
  *(ushort4*)&Wah[(size_t)(i0 + r) * SDIM + j0 + c] = make_ushort4(h[0],h[1],h[2],h[3]);
  *(ushort4*)&Wal[(size_t)(i0 + r) * SDIM + j0 + c] = make_ushort4(l[0],l[1],l[2],l[3]);
  __syncthreads();
  #pragma unroll
  for (int q = 0; q < 4; q++) split2(t[c+q][r], &h[q], &l[q]);
  *(ushort4*)&Wbh[(size_t)(j0 + r) * SDIM + i0 + c] = make_ushort4(h[0],h[1],h[2],h[3]);
  *(ushort4*)&Wbl[(size_t)(j0 + r) * SDIM + i0 + c] = make_ushort4(l[0],l[1],l[2],l[3]);
}

// M = W * W^T. XCD-swizzled 1024-block grid; coalesced float4 writes.
__global__ __launch_bounds__(256) void k_gemmM(const ushort_t* __restrict__ Wah, const ushort_t* __restrict__ Wal,
                                               float* __restrict__ Mmat){
  __shared__ __align__(16) ushort_t smem[16384];
  const int b = blockIdx.x + (blockIdx.y << 5);
  const int xcd = b & 7, slot = b >> 3;
  const int n0 = (((xcd << 2) + (slot >> 5)) << 6);
  const int m0 = ((slot & 31) << 6);
  f32x4 acc[2][2] = {};
  gemm_core(smem, Wah, Wal, Wah, Wal, m0, n0, SDIM, acc);
  acc_to_tile(smem, acc);
  const float* tile = (const float*)smem;
  EPILOGUE_FOR(row, c4)
    f32x4 a = *(const f32x4*)&tile[row*65 + c4];
    *(f32x4*)&Mmat[(size_t)(m0 + row) * SDIM + n0 + c4] = a;
  }
}

// ---------------- Lanczos on M: one kernel per step ----------------
__global__ __launch_bounds__(256) void k_init(float* __restrict__ vRing,
                                              double* __restrict__ dotWV, double* __restrict__ dotWW,
                                              float* __restrict__ betaSq){
  __shared__ float red[256];
  int t = threadIdx.x;
  float vals[8];
  float s = 0.f;
  #pragma unroll
  for (int p = 0; p < 8; p++){
    int j = p*256 + t;
    unsigned h = (unsigned)j * 2654435761u;
    h ^= h >> 16; h *= 2246822519u; h ^= h >> 13;
    float r = (float)(h & 0xFFFFFFu) / 16777216.0f - 0.5f;
    vals[p] = r; s += r*r;
  }
  red[t] = s; __syncthreads();
  for (int o = 128; o > 0; o >>= 1){ if (t < o) red[t] += red[t+o]; __syncthreads(); }
  float inv = rsqrtf(red[0]);
  #pragma unroll
  for (int p = 0; p < 8; p++){
    int j = p*256 + t;
    vRing[SDIM + j] = vals[p]*inv;   // slot 1 = v_1
    vRing[j] = 0.f;                  // slot 0
    vRing[2*SDIM + j] = 0.f;         // slot 2
  }
  if (t < LM+2){ dotWV[t] = 0.0; dotWW[t] = 0.0; betaSq[t] = 0.f; }
}

__global__ __launch_bounds__(256) void k_lstep(const float* __restrict__ M,
    const float* __restrict__ wOld, float* __restrict__ wNew,
    float* __restrict__ vRing, double* __restrict__ dotWV, double* __restrict__ dotWW,
    float* __restrict__ betaSq, int s){
  __shared__ float vs[SDIM];
  __shared__ double pAl[4], pWw[4];
  const int tid = threadIdx.x, bid = blockIdx.x;
  if (s == 1){
    const float* v1 = vRing + SDIM;
    for (int j = tid; j < SDIM; j += 256) vs[j] = v1[j];
  } else {
    const double a  = dotWV[s-1];
    const double ww = dotWW[s-1];
    const float bpSq = betaSq[s-2];
    float bsq = (float)(ww - a*a - (double)bpSq);
    bsq = fmaxf(bsq, 1e-20f);
    const float beta = sqrtf(bsq), invb = 1.0f/beta;
    const float alpha = (float)a, bprev = sqrtf(bpSq);
    const float* vm1 = vRing + ((s-1)%3)*SDIM;
    const float* vm2 = vRing + ((s-2)%3)*SDIM;
    float* vdst = vRing + (s%3)*SDIM;
    for (int j = tid; j < SDIM; j += 256){
      float val = (wOld[j] - alpha*vm1[j] - bprev*vm2[j]) * invb;
      vs[j] = val;
      if (bid == 0) vdst[j] = val;
    }
    if (bid == 0 && tid == 0) betaSq[s-1] = bsq;
  }
  __syncthreads();
  const int wv = tid >> 6, lane = tid & 63;
  const int row = bid*4 + wv;
  const float4* Mr = (const float4*)(M + (size_t)row * SDIM);
  const float4* v4 = (const float4*)vs;
  float acc = 0.f;
  #pragma unroll
  for (int p = 0; p < 8; p++){
    int j4 = p*64 + lane;
    float4 m = Mr[j4], v = v4[j4];
    acc += m.x*v.x + m.y*v.y + m.z*v.z + m.w*v.w;
  }
  #pragma unroll
  for (int o = 32; o > 0; o >>= 1) acc += __shfl_down(acc, o);
  if (lane == 0){
    wNew[row] = acc;
    pAl[wv] = (double)acc * (double)vs[row];
    pWw[wv] = (double)acc * (double)acc;
  }
  __syncthreads();
  if (tid == 0){
    atomicAdd(&dotWV[s], pAl[0]+pAl[1]+pAl[2]+pAl[3]);
    atomicAdd(&dotWW[s], pWw[0]+pWw[1]+pWw[2]+pWw[3]);
  }
}

// lambda_max of tridiagonal via lane-parallel Sturm bisection (fp64)
__global__ void k_sturm(const double* __restrict__ dotWV, const float* __restrict__ betaSq,
                        const float* __restrict__ alphaIn, float* __restrict__ Lbuf){
  __shared__ double sa[LM+1], sb[LM+1];
  int lane = threadIdx.x;
  for (int i = lane; i <= LM; i += 64){
    if (i >= 1){
      sa[i] = dotWV[i];
      sb[i] = (i < LM) ? sqrt((double)betaSq[i]) : 0.0;
    }
  }
  __syncthreads();
  double phi = -1e300, plo = 1e300;
  for (int i = 1 + lane; i <= LM; i += 64){
    double r = (i > 1 ? sb[i-1] : 0.0) + (i < LM ? sb[i] : 0.0);
    phi = fmax(phi, sa[i] + r);
    plo = fmin(plo, sa[i] - r);
  }
  for (int o = 32; o > 0; o >>= 1){
    phi = fmax(phi, __shfl_down(phi, o));
    plo = fmin(plo, __shfl_down(plo, o));
  }
  double hi = __shfl(phi, 0), lo = __shfl(plo, 0);
  for (int round = 0; round < 6; round++){
    double x = lo + (hi - lo) * (double)(lane + 1) / 65.0;
    int cnt = 0;
    double dd = sa[1] - x;
    if (dd < 0) cnt++;
    for (int i = 2; i <= LM; i++){
      double off = sb[i-1];
      if (fabs(dd) < 1e-300) dd = -1e-300;
      dd = sa[i] - x - off*off/dd;
      if (dd < 0) cnt++;
    }
    unsigned long long bal = __ballot(cnt == LM);
    int p = (bal == 0ull) ? 64 : (__ffsll((unsigned long long)bal) - 1);
    double newhi = (p <= 63) ? lo + (hi - lo) * (double)(p + 1) / 65.0 : hi;
    double newlo = (p >= 1)  ? lo + (hi - lo) * (double)p / 65.0       : lo;
    hi = newhi; lo = newlo;
  }
  if (lane == 0){
    double L = 0.5*(lo + hi);
    Lbuf[0] = (float)(1.0 / L);
    Lbuf[1] = (float)(0.5 * (double)alphaIn[0] / L);
  }
}

// ---------------- FISTA ----------------

__global__ __launch_bounds__(256) void k_A0(const float* __restrict__ Y, const float* __restrict__ src,
                                            float* __restrict__ yd, ushort_t* __restrict__ sresh,
                                            ushort_t* __restrict__ sresl, float* __restrict__ out,
                                            const float* __restrict__ Lbuf){
  int idx = blockIdx.x*256 + threadIdx.x;
  float invL = Lbuf[0], th = Lbuf[1];
  float y = Y[idx], s = src[idx];
  split2(s*y, &sresh[idx], &sresl[idx]);
  float xn = softt(y*invL, th);
  int b = idx >> 11, i = idx & 2047;
  out[(size_t)b*4096 + 2048 + i] = xn;
  yd[idx] = xn;   // c0 = 0 -> y1 = x1
}

// XCD swizzle for 512-block FISTA gemms
__device__ __forceinline__ void swz512(int* m0, int* n0){
  const int b = blockIdx.x + (blockIdx.y << 5);
  const int xcd = b & 7, slot = b >> 3;
  *n0 = (((xcd << 2) + (slot >> 4)) << 6);
  *m0 = ((slot & 15) << 6);
}

// GEMM1: acc[b][i] = sum_k ym[b][k]*W[i][k]; fused res/sres/delta update
__global__ __launch_bounds__(256) void k_gemmA(
    const ushort_t* __restrict__ Wah, const ushort_t* __restrict__ Wal,
    const ushort_t* __restrict__ ymh, const ushort_t* __restrict__ yml,
    const float* __restrict__ Y, const float* __restrict__ src,
    float* __restrict__ yd, float* __restrict__ out,
    ushort_t* __restrict__ sresh, ushort_t* __restrict__ sresl,
    const float* __restrict__ Lbuf, float ck)
{
  __shared__ __align__(16) ushort_t smem[16384];
  f32x4 acc[2][2] = {};
  int m0, n0; swz512(&m0, &n0);
  gemm_core(smem, ymh, yml, Wah, Wal, m0, n0, SDIM, acc);
  acc_to_tile(smem, acc);
  const float* tile = (const float*)smem;
  const float invL = Lbuf[0], th = Lbuf[1];
  EPILOGUE_FOR(row, c4)
    const int brow = m0 + row;
    const size_t g  = (size_t)brow*SDIM + n0 + c4;
    const size_t go = (size_t)brow*4096 + 2048 + n0 + c4;
    f32x4 a   = *(const f32x4*)&tile[row*65 + c4];
    f32x4 s4  = *(const f32x4*)&src[g];
    f32x4 y4  = *(const f32x4*)&Y[g];
    f32x4 yd4 = *(const f32x4*)&yd[g];
    f32x4 xo4 = *(const f32x4*)&out[go];
    f32x4 res, xn, yn;
    ushort4 sh, sl;
    #pragma unroll
    for (int q = 0; q < 4; q++){
      res[q] = y4[q] - s4[q]*a[q] - yd4[q];
      xn[q]  = softt(yd4[q] + res[q]*invL, th);
      yn[q]  = xn[q] + ck*(xn[q] - xo4[q]);
    }
    split2(s4[0]*res[0], &sh.x, &sl.x);
    split2(s4[1]*res[1], &sh.y, &sl.y);
    split2(s4[2]*res[2], &sh.z, &sl.z);
    split2(s4[3]*res[3], &sh.w, &sl.w);
    *(ushort4*)&sresh[g] = sh;
    *(ushort4*)&sresl[g] = sl;
    *(f32x4*)&out[go] = xn;
    *(f32x4*)&yd[g]   = yn;
  }
}

// GEMM2: acc[b][j] = sum_i sres[b][i]*W[i][j]; fused theta update
template<bool FIRST>
__global__ __launch_bounds__(256) void k_gemmB(
    const ushort_t* __restrict__ Wbh, const ushort_t* __restrict__ Wbl,
    const ushort_t* __restrict__ sresh, const ushort_t* __restrict__ sresl,
    ushort_t* __restrict__ ymh, ushort_t* __restrict__ yml,
    float* __restrict__ out, const float* __restrict__ Lbuf, float ck)
{
  __shared__ __align__(16) ushort_t smem[16384];
  f32x4 acc[2][2] = {};
  int m0, n0; swz512(&m0, &n0);
  gemm_core(smem, sresh, sresl, Wbh, Wbl, m0, n0, SDIM, acc);
  acc_to_tile(smem, acc);
  const float* tile = (const float*)smem;
  const float invL = Lbuf[0], th = Lbuf[1];
  EPILOGUE_FOR(row, c4)
    const int brow = m0 + row;
    const size_t g  = (size_t)brow*SDIM + n0 + c4;
    const size_t go = (size_t)brow*4096 + n0 + c4;
    f32x4 a = *(const f32x4*)&tile[row*65 + c4];
    f32x4 ym4, xo4;
    if (FIRST){
      ym4 = (f32x4){0.f,0.f,0.f,0.f};
      xo4 = (f32x4){0.f,0.f,0.f,0.f};
    } else {
      ushort4 h4 = *(const ushort4*)&ymh[g];
      ushort4 l4 = *(const ushort4*)&yml[g];
      ym4[0] = bf2f(h4.x) + bf2f(l4.x);
      ym4[1] = bf2f(h4.y) + bf2f(l4.y);
      ym4[2] = bf2f(h4.z) + bf2f(l4.z);
      ym4[3] = bf2f(h4.w) + bf2f(l4.w);
      xo4 = *(const f32x4*)&out[go];
    }
    f32x4 xn, yn;
    ushort4 hh, ll;
    #pragma unroll
    for (int q = 0; q < 4; q++){
      xn[q] = softt(ym4[q] + a[q]*invL, th);
      yn[q] = xn[q] + ck*(xn[q] - xo4[q]);
    }
    split2(yn[0], &hh.x, &ll.x);
    split2(yn[1], &hh.y, &ll.y);
    split2(yn[2], &hh.z, &ll.z);
    split2(yn[3], &hh.w, &ll.w);
    *(f32x4*)&out[go] = xn;
    *(ushort4*)&ymh[g] = hh;
    *(ushort4*)&yml[g] = ll;
  }
}

// ---------------- host ----------------

extern "C" void kernel_launch(void* const* d_in, const int* in_sizes, int n_in,
                              void* d_out, int out_size, void* d_ws, size_t ws_size,
                              hipStream_t stream) {
  const float* src   = (const float*)d_in[0];
  const float* Y     = (const float*)d_in[1];
  const float* W     = (const float*)d_in[2];
  const float* alpha = (const float*)d_in[3];
  float* out = (float*)d_out;
  float* ws  = (float*)d_ws;

  const size_t M1 = 1024*1024;
  float* Mmat = ws;                      // 4M floats (16MB)
  float* yd   = ws + 4*M1;               // 2M floats
  float* lanc = ws + 6*M1;
  float* w0      = lanc;                 // 2048
  float* w1      = lanc + SDIM;          // 2048
  float* vRing   = lanc + 2*SDIM;        // 3*2048
  double* dotWV  = (double*)(lanc + 5*SDIM);        // 128 doubles
  double* dotWW  = dotWV + 128;                     // 128 doubles
  float* betaSq  = lanc + 5*SDIM + 512;             // 128 floats
  float* Lbuf    = betaSq + 128;                    // 2
  ushort_t* u16 = (ushort_t*)(ws + 7*M1);
  ushort_t* Wah = u16;                   // 4M u16 each
  ushort_t* Wal = u16 + 4*M1;
  ushort_t* Wbh = u16 + 8*M1;
  ushort_t* Wbl = u16 + 12*M1;
  ushort_t* ymh = u16 + 16*M1;           // 2M u16 each
  ushort_t* yml = u16 + 18*M1;
  ushort_t* sresh = u16 + 20*M1;
  ushort_t* sresl = u16 + 22*M1;

  // ---- split W (and W^T) into bf16 hi/lo ----
  k_split<<<dim3(64,64), 256, 0, stream>>>(W, Wah, Wal, Wbh, Wbl);
  // ---- M = W W^T for Lanczos ----
  k_gemmM<<<dim3(32,32), 256, 0, stream>>>(Wah, Wal, Mmat);

  // ---- Lanczos for L = lambda_max: one kernel per step ----
  float* wb[2] = { w0, w1 };
  k_init<<<1, 256, 0, stream>>>(vRing, dotWV, dotWW, betaSq);
  for (int s = 1; s <= LM; s++){
    k_lstep<<<512, 256, 0, stream>>>(Mmat, wb[(s+1)&1], wb[s&1], vRing, dotWV, dotWW, betaSq, s);
  }
  k_sturm<<<1, 64, 0, stream>>>(dotWV, betaSq, alpha, Lbuf);

  // ---- momentum coefficients (data independent) ----
  double t = 1.0;
  float ckv[NITER];
  for (int k = 0; k < NITER; k++){
    double tn = 0.5*(1.0 + sqrt(1.0 + 4.0*t*t));
    ckv[k] = (float)((t - 1.0)/tn);
    t = tn;
  }

  // ---- FISTA ----
  k_A0<<<(BATCH*SDIM)/256, 256, 0, stream>>>(Y, src, yd, sresh, sresl, out, Lbuf);
  k_gemmB<true><<<dim3(32,16), 256, 0, stream>>>(Wbh, Wbl, sresh, sresl, ymh, yml, out, Lbuf, ckv[0]);
  for (int k = 1; k < NITER; k++){
    k_gemmA<<<dim3(32,16), 256, 0, stream>>>(Wah, Wal, ymh, yml, Y, src, yd, out, sresh, sresl, Lbuf, ckv[k]);
    k_gemmB<false><<<dim3(32,16), 256, 0, stream>>>(Wbh, Wbl, sresh, sresl, ymh, yml, out, Lbuf, ckv[k]);
  }
  (void)in_sizes; (void)n_in; (void)out_size; (void)ws_size;
}